// Round 9
// baseline (97.547 us; speedup 1.0000x reference)
//
#include <hip/hip_runtime.h>

#define C_IN   64
#define HW_DIM 64
#define C_OUT  128
#define NG     8
#define KSPL   4608     // 576 * 8
#define BM     128      // pixels per block = TWO image rows
#define NSPL_STEPS 72   // KSPL / 64
#define NSTEPS 81
#define NPAD   66
#define NEXP   (8 * C_IN * NPAD * NPAD)   // 2,230,272 padded elements

// d_ws layout (bytes)
#define WT_BYTES 1327104                  // 81*128*64*2
#define XE_OFF   WT_BYTES
#define XE_BYTES (NEXP * NG * 2)          // 35,684,352
#define SE_OFF   (XE_OFF + XE_BYTES)

typedef __attribute__((ext_vector_type(8))) __bf16 bf16x8;
typedef __attribute__((ext_vector_type(4))) float  f32x4;

// --------------------------------------------------------------------------
// Weight prep: pack spline_w ++ base_w into per-co-quarter MFMA-fragment
// order: wt3[step][nq(4)][n(2)][ks(2)][lane(64)][8], value = W[co][k],
// co = nq*32 + n*16 + (lane&15), k = step*64 + ks*32 + (lane>>4)*8 + e.
// --------------------------------------------------------------------------
__global__ __launch_bounds__(256)
void prep_wt(const float* __restrict__ sw, const float* __restrict__ bw,
             __bf16* __restrict__ wt3)
{
  const int step = blockIdx.x;
  const int t    = threadIdx.x;
  const int nq   = t >> 6;
  const int lane = t & 63;
  const int l15  = lane & 15;
  const int g4   = lane >> 4;
#pragma unroll
  for (int n = 0; n < 2; ++n)
#pragma unroll
    for (int ks = 0; ks < 2; ++ks) {
      const int co = nq * 32 + n * 16 + l15;
      bf16x8 v;
#pragma unroll
      for (int e = 0; e < 8; ++e) {
        const int k = step * 64 + ks * 32 + g4 * 8 + e;
        float f;
        if (k < KSPL) f = sw[(size_t)k * C_OUT + co];
        else          f = bw[(size_t)(k - KSPL) * C_OUT + co];
        v[e] = (__bf16)f;
      }
      *(bf16x8*)(wt3 + (size_t)step * 8192 + nq * 2048 + (n * 2 + ks) * 512
                 + lane * 8) = v;
    }
}

// --------------------------------------------------------------------------
// Basis/silu expansion: XE[bc][yp][xp][8], SE[bc][yp][xp]; halo = p=0 values.
// --------------------------------------------------------------------------
__global__ __launch_bounds__(256)
void expand(const float* __restrict__ x, const float* __restrict__ grid,
            __bf16* __restrict__ xe, __bf16* __restrict__ se)
{
  const int idx = blockIdx.x * 256 + threadIdx.x;
  if (idx >= NEXP) return;
  const int xp = idx % NPAD;
  const int r  = idx / NPAD;
  const int yp = r % NPAD;
  const int bc = r / NPAD;

  float p = 0.f;
  if (xp >= 1 && xp <= HW_DIM && yp >= 1 && yp <= HW_DIM)
    p = x[(size_t)bc * (HW_DIM * HW_DIM) + (yp - 1) * HW_DIM + (xp - 1)];

  bf16x8 v;
#pragma unroll
  for (int g = 0; g < NG; ++g) {
    const float z = 1.75f * (p - grid[g]);
    v[g] = (__bf16)__expf(-z * z);
  }
  *(bf16x8*)(xe + (size_t)idx * NG) = v;
  const float e = __expf(-p);
  se[idx] = (__bf16)(p * __builtin_amdgcn_rcpf(1.f + e));
}

static __device__ __forceinline__ void gload16(const __bf16* g, __bf16* l) {
  __builtin_amdgcn_global_load_lds(
      (const __attribute__((address_space(1))) void*)g,
      (__attribute__((address_space(3))) void*)l, 16, 0, 0);
}

// counted-vmcnt barrier (T4): keep 6 newest VMEM ops in flight across it
#define WAITBAR6() do {                                      \
    asm volatile("s_waitcnt vmcnt(6)" ::: "memory");         \
    __builtin_amdgcn_s_barrier();                            \
    __builtin_amdgcn_sched_barrier(0);                       \
  } while (0)

// --------------------------------------------------------------------------
// GEMM: 256 blocks (2 image rows each) x 512 threads (8 waves, each
// 64px x 32co: mh = wid>>2 picks the px-half, nq = wid&3 the co-quarter).
// Spline (72 steps): distance-2 pipeline, 6 VMEM ops/thread/step
// (2 global_load_lds for the 16KB A-tile into a 3-deep LDS ring + 4 b128
// B-frag loads into 3 named register sets), counted vmcnt(6) barriers.
// B-tile is read from L2 once; mh-pair waves dedup through L1.
// Base (9 steps): silu LDS gathers + __syncthreads.
// --------------------------------------------------------------------------
__global__ __launch_bounds__(512, 2)
void kan_gemm(const __bf16* __restrict__ xe, const __bf16* __restrict__ se,
              const __bf16* __restrict__ wt3, const float* __restrict__ base_b,
              float* __restrict__ out)
{
  __shared__ __align__(16) __bf16 As[3][BM][64];   // 3 x 16 KB ring
  __shared__ int tbl[576];                         // c*4356 + kh*66 + kw

  const int t    = threadIdx.x;
  const int lane = t & 63;
  const int wid  = t >> 6;              // 0..7
  const int l15  = lane & 15;
  const int g4   = lane >> 4;
  const int mh   = wid >> 2;            // px half (0: rows 0-63, 1: 64-127)
  const int nq   = wid & 3;             // co quarter

  // bijective XCD swizzle: 256 blocks = 8 XCDs x 32 -> one image per XCD
  const int bid = blockIdx.x;
  const int swz = (bid & 7) * 32 + (bid >> 3);
  const int b   = swz >> 5;             // image (32 blocks each)
  const int y0  = (swz & 31) * 2;       // first image row (even)

  for (int f = t; f < 576; f += 512) {
    const int c  = f / 9;
    const int j  = f - 9 * c;
    const int kh = j / 3;
    const int kw = j - 3 * kh;
    tbl[f] = c * 4356 + kh * 66 + kw;
  }

  const int ROW = b * 278784 + y0 * 66;

  // A-staging: granule g = pass*512 + t -> (px = g>>3, gslot = g&7);
  // slot (px,gslot) holds feature q = gslot ^ (px&7)  (G21 pre-swizzle).
  // px&7 == (t>>3)&7 for both passes (pass offset 64), so qsrc is shared.
  const int qsrc = (t & 7) ^ ((t >> 3) & 7);
  const int xcol = t >> 3;              // x within row, both passes

  f32x4 acc[2][4];
#pragma unroll
  for (int n = 0; n < 2; ++n)
#pragma unroll
    for (int m = 0; m < 4; ++m)
      acc[n][m] = f32x4{0.f, 0.f, 0.f, 0.f};

  auto stageA = [&](int buf, int step) {
    const int off = ROW + tbl[step * 8 + qsrc] + xcol;
    __bf16* dst = &As[buf][0][0] + t * 8;
    gload16(xe + (size_t)off * 8,        dst);           // pass 0: rows y0
    gload16(xe + (size_t)(off + 66) * 8, dst + 4096);    // pass 1: rows y0+1
  };

  auto loadB = [&](bf16x8 (&wf)[2][2], int step) {
    const __bf16* wb = wt3 + (size_t)step * 8192 + nq * 2048 + lane * 8;
#pragma unroll
    for (int n = 0; n < 2; ++n)
#pragma unroll
      for (int ks = 0; ks < 2; ++ks)
        wf[n][ks] = *(const bf16x8*)(wb + (n * 2 + ks) * 512);
  };

  auto compute = [&](int buf, bf16x8 (&wf)[2][2]) {
    bf16x8 xf[4][2];
#pragma unroll
    for (int ks = 0; ks < 2; ++ks)
#pragma unroll
      for (int m = 0; m < 4; ++m) {
        const int pr = mh * 64 + m * 16 + l15;
        xf[m][ks] = *(const bf16x8*)(&As[buf][pr][(((ks * 4 + g4) ^ (pr & 7)) * 8)]);
      }
#pragma unroll
    for (int ks = 0; ks < 2; ++ks)
#pragma unroll
      for (int n = 0; n < 2; ++n)
#pragma unroll
        for (int m = 0; m < 4; ++m)
          acc[n][m] = __builtin_amdgcn_mfma_f32_16x16x32_bf16(
              wf[n][ks], xf[m][ks], acc[n][m], 0, 0, 0);
  };

  __syncthreads();                      // tbl ready

  // ---- spline phase: distance-2 pipeline, counted-vmcnt barriers ----
  bf16x8 wA[2][2], wB[2][2], wC[2][2];
  stageA(0, 0); loadB(wA, 0);           // 6 VMEM ops
  stageA(1, 1); loadB(wB, 1);           // 6 VMEM ops
  WAITBAR6();                           // step-0 landed; step-1 in flight

  for (int s = 0; s < 69; s += 3) {
    stageA(2, s + 2); loadB(wC, s + 2);
    compute(0, wA);
    WAITBAR6();
    stageA(0, s + 3); loadB(wA, s + 3);
    compute(1, wB);
    WAITBAR6();
    stageA(1, s + 4); loadB(wB, s + 4);
    compute(2, wC);
    WAITBAR6();
  }
  // steps 69..71
  stageA(2, 71); loadB(wC, 71);
  compute(0, wA);                       // step 69
  WAITBAR6();                           // A(70) landed
  compute(1, wB);                       // step 70
  asm volatile("s_waitcnt vmcnt(0)" ::: "memory");
  __builtin_amdgcn_s_barrier();
  __builtin_amdgcn_sched_barrier(0);
  compute(2, wC);                       // step 71

  // ---- base phase: silu(p) patches via LDS (9 steps) ----
  auto stageBase = [&](int buf, int bs) {
#pragma unroll
    for (int h = 0; h < 2; ++h) {
      const int px    = h * 64 + (t >> 3);
      const int gslot = t & 7;
      bf16x8 v;
#pragma unroll
      for (int jj = 0; jj < 8; ++jj) {
        const int f = (bs - NSPL_STEPS) * 64 + qsrc * 8 + jj;
        v[jj] = se[(size_t)(ROW + tbl[f] + (px >> 6) * 66 + (px & 63))];
      }
      *(bf16x8*)(&As[buf][px][gslot * 8]) = v;
    }
  };

  stageBase(0, NSPL_STEPS);             // buf0 free (last compute used buf2)
  __syncthreads();
  for (int bs = NSPL_STEPS; bs < NSTEPS; ++bs) {
    const int cb = (bs - NSPL_STEPS) & 1;
    if (bs + 1 < NSTEPS) stageBase(cb ^ 1, bs + 1);
    loadB(wA, bs);
    compute(cb, wA);
    __syncthreads();
  }

  // ---- epilogue: D[co][pix]; l15 -> consecutive x: coalesced ----
#pragma unroll
  for (int n = 0; n < 2; ++n) {
    const int co = nq * 32 + n * 16 + g4 * 4;
#pragma unroll
    for (int m = 0; m < 4; ++m) {
      const int y = y0 + mh;
      const int xcoord = m * 16 + l15;
      float* o = out + (size_t)(b * C_OUT + co) * 4096 + y * 64 + xcoord;
#pragma unroll
      for (int i = 0; i < 4; ++i)
        o[(size_t)i * 4096] = acc[n][m][i] + base_b[co + i];
    }
  }
}

extern "C" void kernel_launch(void* const* d_in, const int* in_sizes, int n_in,
                              void* d_out, int out_size, void* d_ws, size_t ws_size,
                              hipStream_t stream) {
  const float* x    = (const float*)d_in[0];
  const float* grid = (const float*)d_in[1];
  const float* sw   = (const float*)d_in[2];
  const float* bw   = (const float*)d_in[3];
  const float* bb   = (const float*)d_in[4];
  float* out = (float*)d_out;

  __bf16* wt3 = (__bf16*)d_ws;
  __bf16* xe  = (__bf16*)((char*)d_ws + XE_OFF);
  __bf16* se  = (__bf16*)((char*)d_ws + SE_OFF);

  prep_wt<<<NSTEPS, 256, 0, stream>>>(sw, bw, wt3);
  expand<<<(NEXP + 255) / 256, 256, 0, stream>>>(x, grid, xe, se);
  kan_gemm<<<256, 512, 0, stream>>>(xe, se, wt3, bb, out);
}